// Round 1
// baseline (132.337 us; speedup 1.0000x reference)
//
#include <hip/hip_runtime.h>

typedef unsigned short u16;
typedef __attribute__((ext_vector_type(8))) short short8;
typedef __attribute__((ext_vector_type(8))) __bf16 bf16x8;
typedef __attribute__((ext_vector_type(4))) float f32x4;

#define MFMA_BF16(a, b, c) __builtin_amdgcn_mfma_f32_16x16x32_bf16((a), (b), (c), 0, 0, 0)

__device__ __forceinline__ u16 f2bf(float f) {
    unsigned u = __builtin_bit_cast(unsigned, f);
    u += 0x7FFFu + ((u >> 16) & 1u);   // round-to-nearest-even; inputs finite
    return (u16)(u >> 16);
}

// ---------------------------------------------------------------------------
// Projection GEMM: O[n][c] = bf16( (X[n][:] . W[c][:] + b[c]) * alpha )
// X: f32 (4096 x 512), W: f32 (512 x 512) row-major (torch Linear => X @ W.T).
// 128x128 tile, BK=64, 4 waves, XOR-swizzled LDS, reg-staged f32->bf16.
// blockIdx.z selects {query,key,value} so one launch fills the GPU (384 WGs).
// ---------------------------------------------------------------------------
__global__ __launch_bounds__(256) void proj_gemm(
    const float* __restrict__ Xq, const float* __restrict__ Xk, const float* __restrict__ Xv,
    const float* __restrict__ Wq, const float* __restrict__ Wk, const float* __restrict__ Wv,
    const float* __restrict__ bq, const float* __restrict__ bk, const float* __restrict__ bv,
    u16* __restrict__ Oq, u16* __restrict__ Ok, u16* __restrict__ Ov)
{
    constexpr int K = 512, N = 512;
    const int z = blockIdx.z;
    const float* __restrict__ X = (z == 0) ? Xq : (z == 1) ? Xk : Xv;
    const float* __restrict__ W = (z == 0) ? Wq : (z == 1) ? Wk : Wv;
    const float* __restrict__ bias = (z == 0) ? bq : (z == 1) ? bk : bv;
    u16* __restrict__ O = (z == 0) ? Oq : (z == 1) ? Ok : Ov;
    const float alpha = (z == 0) ? 0.125f : 1.0f;   // fold softmax scale into Q (exact pow2)

    __shared__ u16 lA[128 * 64];
    __shared__ u16 lB[128 * 64];

    const int tid = threadIdx.x, lane = tid & 63, w = tid >> 6;
    const int wr = w >> 1, wc = w & 1;
    const int bm = blockIdx.x, bn = blockIdx.y;
    const int r0 = tid >> 3, cc = tid & 7;

    f32x4 acc[4][4];
    for (int m = 0; m < 4; ++m)
        for (int n = 0; n < 4; ++n)
            acc[m][n] = f32x4{0.f, 0.f, 0.f, 0.f};

    for (int kt = 0; kt < K; kt += 64) {
        __syncthreads();
        // stage A (X) and B (W): 128 rows x 64 cols each, f32 -> bf16, swizzled
        for (int p = 0; p < 4; ++p) {
            int r = r0 + p * 32;
            {
                const float4* g = (const float4*)(X + (size_t)(bm * 128 + r) * K + kt + cc * 8);
                float4 f0 = g[0], f1 = g[1];
                short8 v;
                v[0] = (short)f2bf(f0.x); v[1] = (short)f2bf(f0.y);
                v[2] = (short)f2bf(f0.z); v[3] = (short)f2bf(f0.w);
                v[4] = (short)f2bf(f1.x); v[5] = (short)f2bf(f1.y);
                v[6] = (short)f2bf(f1.z); v[7] = (short)f2bf(f1.w);
                *(short8*)&lA[r * 64 + ((cc ^ (r & 7)) << 3)] = v;
            }
            {
                const float4* g = (const float4*)(W + (size_t)(bn * 128 + r) * K + kt + cc * 8);
                float4 f0 = g[0], f1 = g[1];
                short8 v;
                v[0] = (short)f2bf(f0.x); v[1] = (short)f2bf(f0.y);
                v[2] = (short)f2bf(f0.z); v[3] = (short)f2bf(f0.w);
                v[4] = (short)f2bf(f1.x); v[5] = (short)f2bf(f1.y);
                v[6] = (short)f2bf(f1.z); v[7] = (short)f2bf(f1.w);
                *(short8*)&lB[r * 64 + ((cc ^ (r & 7)) << 3)] = v;
            }
        }
        __syncthreads();
        for (int kk = 0; kk < 2; ++kk) {
            bf16x8 af[4], bfr[4];
            for (int m = 0; m < 4; ++m) {
                int row = wr * 64 + m * 16 + (lane & 15);
                af[m] = *(const bf16x8*)&lA[row * 64 + (((kk * 4 + (lane >> 4)) ^ (row & 7)) << 3)];
            }
            for (int n = 0; n < 4; ++n) {
                int row = wc * 64 + n * 16 + (lane & 15);
                bfr[n] = *(const bf16x8*)&lB[row * 64 + (((kk * 4 + (lane >> 4)) ^ (row & 7)) << 3)];
            }
            for (int m = 0; m < 4; ++m)
                for (int n = 0; n < 4; ++n)
                    acc[m][n] = MFMA_BF16(af[m], bfr[n], acc[m][n]);
        }
    }
    // epilogue: C/D layout row=(lane>>4)*4+i, col=lane&15  [m89-verified]
    for (int m = 0; m < 4; ++m)
        for (int n = 0; n < 4; ++n) {
            int row = bm * 128 + wr * 64 + m * 16 + ((lane >> 4) << 2);
            int col = bn * 128 + wc * 64 + n * 16 + (lane & 15);
            float bv_ = bias[col];
            for (int i = 0; i < 4; ++i) {
                float v = (acc[m][n][i] + bv_) * alpha;
                O[(size_t)(row + i) * N + col] = f2bf(v);
            }
        }
}

// ---------------------------------------------------------------------------
// Output GEMM: out[n][c] = f32( A[n][:] . Wo[c][:] + bo[c] ), A bf16, Wo f32.
// ---------------------------------------------------------------------------
__global__ __launch_bounds__(256) void out_gemm(
    const u16* __restrict__ A, const float* __restrict__ W,
    const float* __restrict__ bias, float* __restrict__ O)
{
    constexpr int K = 512, N = 512;
    __shared__ u16 lA[128 * 64];
    __shared__ u16 lB[128 * 64];

    const int tid = threadIdx.x, lane = tid & 63, w = tid >> 6;
    const int wr = w >> 1, wc = w & 1;
    const int bm = blockIdx.x, bn = blockIdx.y;
    const int r0 = tid >> 3, cc = tid & 7;

    f32x4 acc[4][4];
    for (int m = 0; m < 4; ++m)
        for (int n = 0; n < 4; ++n)
            acc[m][n] = f32x4{0.f, 0.f, 0.f, 0.f};

    for (int kt = 0; kt < K; kt += 64) {
        __syncthreads();
        for (int p = 0; p < 4; ++p) {
            int r = r0 + p * 32;
            *(short8*)&lA[r * 64 + ((cc ^ (r & 7)) << 3)] =
                *(const short8*)(A + (size_t)(bm * 128 + r) * K + kt + cc * 8);
            const float4* g = (const float4*)(W + (size_t)(bn * 128 + r) * K + kt + cc * 8);
            float4 f0 = g[0], f1 = g[1];
            short8 v;
            v[0] = (short)f2bf(f0.x); v[1] = (short)f2bf(f0.y);
            v[2] = (short)f2bf(f0.z); v[3] = (short)f2bf(f0.w);
            v[4] = (short)f2bf(f1.x); v[5] = (short)f2bf(f1.y);
            v[6] = (short)f2bf(f1.z); v[7] = (short)f2bf(f1.w);
            *(short8*)&lB[r * 64 + ((cc ^ (r & 7)) << 3)] = v;
        }
        __syncthreads();
        for (int kk = 0; kk < 2; ++kk) {
            bf16x8 af[4], bfr[4];
            for (int m = 0; m < 4; ++m) {
                int row = wr * 64 + m * 16 + (lane & 15);
                af[m] = *(const bf16x8*)&lA[row * 64 + (((kk * 4 + (lane >> 4)) ^ (row & 7)) << 3)];
            }
            for (int n = 0; n < 4; ++n) {
                int row = wc * 64 + n * 16 + (lane & 15);
                bfr[n] = *(const bf16x8*)&lB[row * 64 + (((kk * 4 + (lane >> 4)) ^ (row & 7)) << 3)];
            }
            for (int m = 0; m < 4; ++m)
                for (int n = 0; n < 4; ++n)
                    acc[m][n] = MFMA_BF16(af[m], bfr[n], acc[m][n]);
        }
    }
    for (int m = 0; m < 4; ++m)
        for (int n = 0; n < 4; ++n) {
            int row = bm * 128 + wr * 64 + m * 16 + ((lane >> 4) << 2);
            int col = bn * 128 + wc * 64 + n * 16 + (lane & 15);
            float bv_ = bias[col];
            for (int i = 0; i < 4; ++i)
                O[(size_t)(row + i) * N + col] = acc[m][n][i] + bv_;
        }
}

// ---------------------------------------------------------------------------
// Flash attention: per block one (b,h) and a 64-row q-tile. 4 waves, each owns
// 16 q rows. KVBLK=64. Online softmax in f32; scale pre-folded into Qp.
// Qp/Kp/Vp: bf16 (4096 x 512), head h occupies cols [h*64, h*64+64).
// ---------------------------------------------------------------------------
__global__ __launch_bounds__(256) void attn_k(
    const u16* __restrict__ Qp, const u16* __restrict__ Kp, const u16* __restrict__ Vp,
    const unsigned char* __restrict__ mask, u16* __restrict__ Ob)
{
    constexpr int C = 512, NK = 2048;
    __shared__ u16 lQ[64 * 64];
    __shared__ u16 lK[64 * 64];
    __shared__ u16 lV[64 * 64];   // transposed: lV[d][kv]
    __shared__ u16 lP[64 * 64];   // P[q][kv], rows wave-private

    const int tid = threadIdx.x, lane = tid & 63, w = tid >> 6;
    const int qb = blockIdx.x, bh = blockIdx.y;
    const int b = bh >> 3, h = bh & 7;
    const size_t qrow0 = (size_t)b * 2048 + qb * 64;
    const size_t krow0 = (size_t)b * 2048;
    const int col0 = h * 64;
    const int r0 = tid >> 3, cc = tid & 7;

    // stage Q tile (64 x 64), swizzled
    for (int p = 0; p < 2; ++p) {
        int r = r0 + p * 32;
        *(short8*)&lQ[r * 64 + ((cc ^ (r & 7)) << 3)] =
            *(const short8*)(Qp + (qrow0 + r) * C + col0 + cc * 8);
    }

    float mst[4], lst[4];
    f32x4 oacc[4];
    for (int i = 0; i < 4; ++i) { mst[i] = -1e30f; lst[i] = 0.f; oacc[i] = f32x4{0.f, 0.f, 0.f, 0.f}; }
    __syncthreads();

    for (int kv = 0; kv < NK; kv += 64) {
        // stage K (row-major swizzled) and V (transposed swizzled)
        for (int p = 0; p < 2; ++p) {
            int r = r0 + p * 32;
            *(short8*)&lK[r * 64 + ((cc ^ (r & 7)) << 3)] =
                *(const short8*)(Kp + (krow0 + kv + r) * C + col0 + cc * 8);
            short8 vv = *(const short8*)(Vp + (krow0 + kv + r) * C + col0 + cc * 8);
            for (int j = 0; j < 8; ++j) {
                int d = cc * 8 + j;
                lV[d * 64 + (((r >> 3) ^ (d & 7)) << 3) + (r & 7)] = (u16)vv[j];
            }
        }
        __syncthreads();

        // S = Q . K^T   (scale already folded into Q)
        f32x4 s[4];
        for (int t = 0; t < 4; ++t) s[t] = f32x4{0.f, 0.f, 0.f, 0.f};
        for (int kk = 0; kk < 2; ++kk) {
            int qrow = w * 16 + (lane & 15);
            bf16x8 aq = *(const bf16x8*)&lQ[qrow * 64 + (((kk * 4 + (lane >> 4)) ^ (qrow & 7)) << 3)];
            for (int t = 0; t < 4; ++t) {
                int krow = t * 16 + (lane & 15);
                bf16x8 bk = *(const bf16x8*)&lK[krow * 64 + (((kk * 4 + (lane >> 4)) ^ (krow & 7)) << 3)];
                s[t] = MFMA_BF16(aq, bk, s[t]);
            }
        }

        // key padding mask (all-false for this input; bytes are 0 under bool or int32)
        for (int t = 0; t < 4; ++t) {
            if (mask[(size_t)b * NK + kv + t * 16 + (lane & 15)]) {
                for (int i = 0; i < 4; ++i) s[t][i] = -1e30f;
            }
        }

        // online softmax; lane's rows are (lane>>4)*4 + i, cols t*16 + (lane&15)
        float rmax[4], rsum[4], sf[4];
        for (int i = 0; i < 4; ++i)
            rmax[i] = fmaxf(fmaxf(s[0][i], s[1][i]), fmaxf(s[2][i], s[3][i]));
        for (int d = 1; d < 16; d <<= 1)
            for (int i = 0; i < 4; ++i) rmax[i] = fmaxf(rmax[i], __shfl_xor(rmax[i], d));
        for (int i = 0; i < 4; ++i) {
            float mn = fmaxf(mst[i], rmax[i]);
            sf[i] = __expf(mst[i] - mn);
            mst[i] = mn;
            rsum[i] = 0.f;
        }
        const int qw = w * 16 + ((lane >> 4) << 2);
        for (int t = 0; t < 4; ++t) {
            int k = t * 16 + (lane & 15);
            for (int i = 0; i < 4; ++i) {
                float p = __expf(s[t][i] - mst[i]);
                rsum[i] += p;
                int q = qw + i;
                lP[q * 64 + (((k >> 3) ^ (q & 7)) << 3) + (k & 7)] = f2bf(p);
            }
        }
        for (int d = 1; d < 16; d <<= 1)
            for (int i = 0; i < 4; ++i) rsum[i] += __shfl_xor(rsum[i], d);
        for (int i = 0; i < 4; ++i) {
            lst[i] = lst[i] * sf[i] + rsum[i];
            for (int t2 = 0; t2 < 4; ++t2) oacc[t2][i] *= sf[i];
        }

        // PV: O[q][d] += P[q][:] . V[:][d]  (P rows wave-private -> no barrier)
        for (int kb = 0; kb < 2; ++kb) {
            int prow = w * 16 + (lane & 15);
            bf16x8 ap = *(const bf16x8*)&lP[prow * 64 + (((kb * 4 + (lane >> 4)) ^ (prow & 7)) << 3)];
            for (int t2 = 0; t2 < 4; ++t2) {
                int vrow = t2 * 16 + (lane & 15);
                bf16x8 bv = *(const bf16x8*)&lV[vrow * 64 + (((kb * 4 + (lane >> 4)) ^ (vrow & 7)) << 3)];
                oacc[t2] = MFMA_BF16(ap, bv, oacc[t2]);
            }
        }
        __syncthreads();   // before next tile overwrites lK/lV
    }

    // epilogue: normalize and store to (B*Nq, C) bf16 at head column block
    for (int t2 = 0; t2 < 4; ++t2) {
        int col = col0 + t2 * 16 + (lane & 15);
        for (int i = 0; i < 4; ++i) {
            int q = qb * 64 + w * 16 + ((lane >> 4) << 2) + i;
            float v = oacc[t2][i] / lst[i];
            Ob[((size_t)b * 2048 + q) * C + col] = f2bf(v);
        }
    }
}

extern "C" void kernel_launch(void* const* d_in, const int* in_sizes, int n_in,
                              void* d_out, int out_size, void* d_ws, size_t ws_size,
                              hipStream_t stream) {
    const float* query = (const float*)d_in[0];
    const float* key   = (const float*)d_in[1];
    const float* value = (const float*)d_in[2];
    const unsigned char* mask = (const unsigned char*)d_in[3];
    const float* Wq = (const float*)d_in[4];
    const float* bq = (const float*)d_in[5];
    const float* Wk = (const float*)d_in[6];
    const float* bk = (const float*)d_in[7];
    const float* Wv = (const float*)d_in[8];
    const float* bv = (const float*)d_in[9];
    const float* Wo = (const float*)d_in[10];
    const float* bo = (const float*)d_in[11];

    // workspace layout (bf16 elements): Qp | Kp | Vp | Ob  == 16 MB total
    u16* ws = (u16*)d_ws;
    u16* Qp = ws;
    u16* Kp = ws + 2097152;
    u16* Vp = ws + 4194304;
    u16* Ob = ws + 6291456;

    dim3 gp(32, 4, 3);
    proj_gemm<<<gp, 256, 0, stream>>>(query, key, value, Wq, Wk, Wv, bq, bk, bv, Qp, Kp, Vp);

    dim3 ga(32, 16);
    attn_k<<<ga, 256, 0, stream>>>(Qp, Kp, Vp, mask, Ob);

    dim3 go(32, 4);
    out_gemm<<<go, 256, 0, stream>>>(Ob, Wo, bo, (float*)d_out);
}

// Round 3
// 112.894 us; speedup vs baseline: 1.1722x; 1.1722x over previous
//
#include <hip/hip_runtime.h>

typedef unsigned short u16;
typedef __attribute__((ext_vector_type(8))) short short8;
typedef __attribute__((ext_vector_type(8))) __bf16 bf16x8;
typedef __attribute__((ext_vector_type(4))) float f32x4;
typedef __attribute__((ext_vector_type(4))) unsigned int u32x4;

#define MFMA_BF16(a, b, c) __builtin_amdgcn_mfma_f32_16x16x32_bf16((a), (b), (c), 0, 0, 0)

__device__ __forceinline__ u16 f2bf(float f) {
    unsigned u = __builtin_bit_cast(unsigned, f);
    u += 0x7FFFu + ((u >> 16) & 1u);   // round-to-nearest-even; inputs finite
    return (u16)(u >> 16);
}

__device__ __forceinline__ unsigned pack_bf2(float lo, float hi) {
    return (unsigned)f2bf(lo) | ((unsigned)f2bf(hi) << 16);
}

// ---------------------------------------------------------------------------
// Projection GEMM: O[n][c] = bf16( (X[n][:] . W[c][:] + b[c]) * alpha )
// ---------------------------------------------------------------------------
__global__ __launch_bounds__(256) void proj_gemm(
    const float* __restrict__ Xq, const float* __restrict__ Xk, const float* __restrict__ Xv,
    const float* __restrict__ Wq, const float* __restrict__ Wk, const float* __restrict__ Wv,
    const float* __restrict__ bq, const float* __restrict__ bk, const float* __restrict__ bv,
    u16* __restrict__ Oq, u16* __restrict__ Ok, u16* __restrict__ Ov)
{
    constexpr int K = 512, N = 512;
    const int z = blockIdx.z;
    const float* __restrict__ X = (z == 0) ? Xq : (z == 1) ? Xk : Xv;
    const float* __restrict__ W = (z == 0) ? Wq : (z == 1) ? Wk : Wv;
    const float* __restrict__ bias = (z == 0) ? bq : (z == 1) ? bk : bv;
    u16* __restrict__ O = (z == 0) ? Oq : (z == 1) ? Ok : Ov;
    const float alpha = (z == 0) ? 0.125f : 1.0f;

    __shared__ u16 lA[128 * 64];
    __shared__ u16 lB[128 * 64];

    const int tid = threadIdx.x, lane = tid & 63, w = tid >> 6;
    const int wr = w >> 1, wc = w & 1;
    const int bm = blockIdx.x, bn = blockIdx.y;
    const int r0 = tid >> 3, cc = tid & 7;

    f32x4 acc[4][4];
    for (int m = 0; m < 4; ++m)
        for (int n = 0; n < 4; ++n)
            acc[m][n] = f32x4{0.f, 0.f, 0.f, 0.f};

    for (int kt = 0; kt < K; kt += 64) {
        __syncthreads();
        for (int p = 0; p < 4; ++p) {
            int r = r0 + p * 32;
            {
                const float4* g = (const float4*)(X + (size_t)(bm * 128 + r) * K + kt + cc * 8);
                float4 f0 = g[0], f1 = g[1];
                short8 v;
                v[0] = (short)f2bf(f0.x); v[1] = (short)f2bf(f0.y);
                v[2] = (short)f2bf(f0.z); v[3] = (short)f2bf(f0.w);
                v[4] = (short)f2bf(f1.x); v[5] = (short)f2bf(f1.y);
                v[6] = (short)f2bf(f1.z); v[7] = (short)f2bf(f1.w);
                *(short8*)&lA[r * 64 + ((cc ^ (r & 7)) << 3)] = v;
            }
            {
                const float4* g = (const float4*)(W + (size_t)(bn * 128 + r) * K + kt + cc * 8);
                float4 f0 = g[0], f1 = g[1];
                short8 v;
                v[0] = (short)f2bf(f0.x); v[1] = (short)f2bf(f0.y);
                v[2] = (short)f2bf(f0.z); v[3] = (short)f2bf(f0.w);
                v[4] = (short)f2bf(f1.x); v[5] = (short)f2bf(f1.y);
                v[6] = (short)f2bf(f1.z); v[7] = (short)f2bf(f1.w);
                *(short8*)&lB[r * 64 + ((cc ^ (r & 7)) << 3)] = v;
            }
        }
        __syncthreads();
        for (int kk = 0; kk < 2; ++kk) {
            bf16x8 af[4], bfr[4];
            for (int m = 0; m < 4; ++m) {
                int row = wr * 64 + m * 16 + (lane & 15);
                af[m] = *(const bf16x8*)&lA[row * 64 + (((kk * 4 + (lane >> 4)) ^ (row & 7)) << 3)];
            }
            for (int n = 0; n < 4; ++n) {
                int row = wc * 64 + n * 16 + (lane & 15);
                bfr[n] = *(const bf16x8*)&lB[row * 64 + (((kk * 4 + (lane >> 4)) ^ (row & 7)) << 3)];
            }
            for (int m = 0; m < 4; ++m)
                for (int n = 0; n < 4; ++n)
                    acc[m][n] = MFMA_BF16(af[m], bfr[n], acc[m][n]);
        }
    }
    for (int m = 0; m < 4; ++m)
        for (int n = 0; n < 4; ++n) {
            int row = bm * 128 + wr * 64 + m * 16 + ((lane >> 4) << 2);
            int col = bn * 128 + wc * 64 + n * 16 + (lane & 15);
            float bv_ = bias[col];
            for (int i = 0; i < 4; ++i) {
                float v = (acc[m][n][i] + bv_) * alpha;
                O[(size_t)(row + i) * N + col] = f2bf(v);
            }
        }
}

// ---------------------------------------------------------------------------
// Output GEMM
// ---------------------------------------------------------------------------
__global__ __launch_bounds__(256) void out_gemm(
    const u16* __restrict__ A, const float* __restrict__ W,
    const float* __restrict__ bias, float* __restrict__ O)
{
    constexpr int K = 512, N = 512;
    __shared__ u16 lA[128 * 64];
    __shared__ u16 lB[128 * 64];

    const int tid = threadIdx.x, lane = tid & 63, w = tid >> 6;
    const int wr = w >> 1, wc = w & 1;
    const int bm = blockIdx.x, bn = blockIdx.y;
    const int r0 = tid >> 3, cc = tid & 7;

    f32x4 acc[4][4];
    for (int m = 0; m < 4; ++m)
        for (int n = 0; n < 4; ++n)
            acc[m][n] = f32x4{0.f, 0.f, 0.f, 0.f};

    for (int kt = 0; kt < K; kt += 64) {
        __syncthreads();
        for (int p = 0; p < 4; ++p) {
            int r = r0 + p * 32;
            *(short8*)&lA[r * 64 + ((cc ^ (r & 7)) << 3)] =
                *(const short8*)(A + (size_t)(bm * 128 + r) * K + kt + cc * 8);
            const float4* g = (const float4*)(W + (size_t)(bn * 128 + r) * K + kt + cc * 8);
            float4 f0 = g[0], f1 = g[1];
            short8 v;
            v[0] = (short)f2bf(f0.x); v[1] = (short)f2bf(f0.y);
            v[2] = (short)f2bf(f0.z); v[3] = (short)f2bf(f0.w);
            v[4] = (short)f2bf(f1.x); v[5] = (short)f2bf(f1.y);
            v[6] = (short)f2bf(f1.z); v[7] = (short)f2bf(f1.w);
            *(short8*)&lB[r * 64 + ((cc ^ (r & 7)) << 3)] = v;
        }
        __syncthreads();
        for (int kk = 0; kk < 2; ++kk) {
            bf16x8 af[4], bfr[4];
            for (int m = 0; m < 4; ++m) {
                int row = wr * 64 + m * 16 + (lane & 15);
                af[m] = *(const bf16x8*)&lA[row * 64 + (((kk * 4 + (lane >> 4)) ^ (row & 7)) << 3)];
            }
            for (int n = 0; n < 4; ++n) {
                int row = wc * 64 + n * 16 + (lane & 15);
                bfr[n] = *(const bf16x8*)&lB[row * 64 + (((kk * 4 + (lane >> 4)) ^ (row & 7)) << 3)];
            }
            for (int m = 0; m < 4; ++m)
                for (int n = 0; n < 4; ++n)
                    acc[m][n] = MFMA_BF16(af[m], bfr[n], acc[m][n]);
        }
    }
    for (int m = 0; m < 4; ++m)
        for (int n = 0; n < 4; ++n) {
            int row = bm * 128 + wr * 64 + m * 16 + ((lane >> 4) << 2);
            int col = bn * 128 + wc * 64 + n * 16 + (lane & 15);
            float bv_ = bias[col];
            for (int i = 0; i < 4; ++i)
                O[(size_t)(row + i) * N + col] = acc[m][n][i] + bv_;
        }
}

// ---------------------------------------------------------------------------
// Flash attention v2: swapped QK^T (S^T = K.Q^T), P in registers, shfl
// redistribution, Q in registers, double-buffered K/V with one barrier/tile.
// Grid: (16 bh, 32 qb) so all q-blocks of one head land on the same XCD.
// ---------------------------------------------------------------------------
__global__ __launch_bounds__(256) void attn_k(
    const u16* __restrict__ Qp, const u16* __restrict__ Kp, const u16* __restrict__ Vp,
    const unsigned char* __restrict__ mask, u16* __restrict__ Ob)
{
    constexpr int C = 512, NK = 2048, NT = NK / 64;
    __shared__ u16 lK[2][64 * 64];
    __shared__ u16 lV[2][64 * 64];   // transposed: lV[buf][d][kv], swizzled

    const int tid = threadIdx.x, lane = tid & 63, w = tid >> 6;
    const int gd = lane >> 4, q15 = lane & 15;
    const int bh = blockIdx.x, qb = blockIdx.y;
    const int b = bh >> 3, h = bh & 7;
    const size_t qrow0 = (size_t)b * 2048 + qb * 64;
    const size_t krow0 = (size_t)b * 2048;
    const int col0 = h * 64;
    const int rs = tid >> 3, cc = tid & 7;

    // Q fragments hoisted to registers: B-operand, lane holds Q[q15][kb*32+gd*8 ..+8]
    bf16x8 qf[2];
    {
        const u16* qrow = Qp + (qrow0 + w * 16 + q15) * C + col0;
        qf[0] = *(const bf16x8*)(qrow + gd * 8);
        qf[1] = *(const bf16x8*)(qrow + 32 + gd * 8);
    }

    // shfl source lanes for P redistribution (group g = (2*gd + (r>>1)) & 3)
    const int src0 = (((2 * gd + 0) & 3) << 4) + q15;
    const int src1 = (((2 * gd + 1) & 3) << 4) + q15;

    float mst = -1e30f, lst = 0.f;
    f32x4 oacc[4];
    #pragma unroll
    for (int i = 0; i < 4; ++i) oacc[i] = f32x4{0.f, 0.f, 0.f, 0.f};

    // prologue: stage tile 0 into buffer 0
    #pragma unroll
    for (int p = 0; p < 2; ++p) {
        int r = rs + p * 32;
        *(short8*)&lK[0][r * 64 + ((cc ^ (r & 7)) << 3)] =
            *(const short8*)(Kp + (krow0 + r) * C + col0 + cc * 8);
        short8 vv = *(const short8*)(Vp + (krow0 + r) * C + col0 + cc * 8);
        #pragma unroll
        for (int j = 0; j < 8; ++j)
            lV[0][(cc * 8 + j) * 64 + (((r >> 3) ^ j) << 3) + (r & 7)] = (u16)vv[j];
    }
    __syncthreads();

    int cur = 0;
    for (int t = 0; t < NT; ++t) {
        const int kv = t * 64;
        const bool hasnext = (t + 1 < NT);
        short8 kreg[2], vreg[2];
        if (hasnext) {
            #pragma unroll
            for (int p = 0; p < 2; ++p) {
                int r = rs + p * 32;
                kreg[p] = *(const short8*)(Kp + (krow0 + kv + 64 + r) * C + col0 + cc * 8);
                vreg[p] = *(const short8*)(Vp + (krow0 + kv + 64 + r) * C + col0 + cc * 8);
            }
        }
        unsigned char mbyte = mask[(size_t)b * NK + kv + lane];

        // QK^T swapped: S^T[k][q]; lane holds k = t4*16 + gd*4 + i for q = q15
        f32x4 s[4];
        #pragma unroll
        for (int i = 0; i < 4; ++i) s[i] = f32x4{0.f, 0.f, 0.f, 0.f};
        const u16* Kc = &lK[cur][0];
        __builtin_amdgcn_s_setprio(1);
        #pragma unroll
        for (int kb = 0; kb < 2; ++kb)
            #pragma unroll
            for (int t4 = 0; t4 < 4; ++t4) {
                int krow = t4 * 16 + q15;
                bf16x8 kf = *(const bf16x8*)&Kc[krow * 64 + (((kb * 4 + gd) ^ (krow & 7)) << 3)];
                s[t4] = MFMA_BF16(kf, qf[kb], s[t4]);
            }
        __builtin_amdgcn_s_setprio(0);

        // key-padding mask (uniform branch; all-false for this input)
        unsigned long long mb = __ballot(mbyte != 0);
        if (mb) {
            #pragma unroll
            for (int t4 = 0; t4 < 4; ++t4)
                #pragma unroll
                for (int i = 0; i < 4; ++i) {
                    int k = t4 * 16 + gd * 4 + i;
                    if ((mb >> k) & 1ull) s[t4][i] = -1e30f;
                }
        }

        // online softmax: lane owns a full row slice of 16 scores for q=q15
        float pmax = s[0][0];
        #pragma unroll
        for (int t4 = 0; t4 < 4; ++t4)
            #pragma unroll
            for (int i = 0; i < 4; ++i) pmax = fmaxf(pmax, s[t4][i]);
        pmax = fmaxf(pmax, __shfl_xor(pmax, 16));
        pmax = fmaxf(pmax, __shfl_xor(pmax, 32));
        float mn = fmaxf(mst, pmax);
        float sf = __expf(mst - mn);
        mst = mn;
        float p[4][4];
        float rsum = 0.f;
        #pragma unroll
        for (int t4 = 0; t4 < 4; ++t4)
            #pragma unroll
            for (int i = 0; i < 4; ++i) {
                float e = __expf(s[t4][i] - mst);
                p[t4][i] = e;
                rsum += e;
            }
        rsum += __shfl_xor(rsum, 16);
        rsum += __shfl_xor(rsum, 32);
        lst = lst * sf + rsum;

        // rescale O: oacc row i belongs to q' = gd*4+i -> pull sf from a lane owning q'
        #pragma unroll
        for (int i = 0; i < 4; ++i) {
            float sfi = __shfl(sf, (lane & 48) | ((gd << 2) + i));
            #pragma unroll
            for (int t2 = 0; t2 < 4; ++t2) oacc[t2][i] *= sfi;
        }

        // pack P to bf16 pairs: pk[t4][j] = (p[t4][2j], p[t4][2j+1])
        unsigned pk[4][2];
        #pragma unroll
        for (int t4 = 0; t4 < 4; ++t4)
            #pragma unroll
            for (int j = 0; j < 2; ++j)
                pk[t4][j] = pack_bf2(p[t4][2 * j], p[t4][2 * j + 1]);

        // redistribute to PV A-frags: pa[kb] reg r holds P[q15][kb*32 + gd*8 + 2r, +1]
        u32x4 paw[2];
        #pragma unroll
        for (int kb = 0; kb < 2; ++kb)
            #pragma unroll
            for (int r = 0; r < 4; ++r) {
                int sl = (r < 2) ? src0 : src1;
                unsigned lo = (unsigned)__shfl((int)pk[2 * kb + 0][r & 1], sl);
                unsigned hi = (unsigned)__shfl((int)pk[2 * kb + 1][r & 1], sl);
                paw[kb][r] = (gd >> 1) ? hi : lo;
            }
        bf16x8 pa0 = __builtin_bit_cast(bf16x8, paw[0]);
        bf16x8 pa1 = __builtin_bit_cast(bf16x8, paw[1]);

        // PV: oacc[t2] += P . V   (B-frag = V columns from transposed lV)
        const u16* Vc = &lV[cur][0];
        __builtin_amdgcn_s_setprio(1);
        #pragma unroll
        for (int kb = 0; kb < 2; ++kb) {
            bf16x8 pa = kb ? pa1 : pa0;
            #pragma unroll
            for (int t2 = 0; t2 < 4; ++t2) {
                int vrow = t2 * 16 + q15;
                bf16x8 vf = *(const bf16x8*)&Vc[vrow * 64 + (((kb * 4 + gd) ^ (vrow & 7)) << 3)];
                oacc[t2] = MFMA_BF16(pa, vf, oacc[t2]);
            }
        }
        __builtin_amdgcn_s_setprio(0);

        // write next tile into the other buffer, single barrier per tile
        if (hasnext) {
            int nxt = cur ^ 1;
            #pragma unroll
            for (int p = 0; p < 2; ++p) {
                int r = rs + p * 32;
                *(short8*)&lK[nxt][r * 64 + ((cc ^ (r & 7)) << 3)] = kreg[p];
                #pragma unroll
                for (int j = 0; j < 8; ++j)
                    lV[nxt][(cc * 8 + j) * 64 + (((r >> 3) ^ j) << 3) + (r & 7)] = (u16)vreg[p][j];
            }
            __syncthreads();
            cur = nxt;
        }
    }

    // epilogue: normalize and store
    #pragma unroll
    for (int i = 0; i < 4; ++i) {
        float li = __shfl(lst, (lane & 48) | ((gd << 2) + i));
        float inv = 1.f / li;
        int qg = qb * 64 + w * 16 + gd * 4 + i;
        #pragma unroll
        for (int t2 = 0; t2 < 4; ++t2) {
            int col = col0 + t2 * 16 + q15;
            Ob[((size_t)b * 2048 + qg) * C + col] = f2bf(oacc[t2][i] * inv);
        }
    }
}

extern "C" void kernel_launch(void* const* d_in, const int* in_sizes, int n_in,
                              void* d_out, int out_size, void* d_ws, size_t ws_size,
                              hipStream_t stream) {
    const float* query = (const float*)d_in[0];
    const float* key   = (const float*)d_in[1];
    const float* value = (const float*)d_in[2];
    const unsigned char* mask = (const unsigned char*)d_in[3];
    const float* Wq = (const float*)d_in[4];
    const float* bq = (const float*)d_in[5];
    const float* Wk = (const float*)d_in[6];
    const float* bk = (const float*)d_in[7];
    const float* Wv = (const float*)d_in[8];
    const float* bv = (const float*)d_in[9];
    const float* Wo = (const float*)d_in[10];
    const float* bo = (const float*)d_in[11];

    u16* ws = (u16*)d_ws;
    u16* Qp = ws;
    u16* Kp = ws + 2097152;
    u16* Vp = ws + 4194304;
    u16* Ob = ws + 6291456;

    dim3 gp(32, 4, 3);
    proj_gemm<<<gp, 256, 0, stream>>>(query, key, value, Wq, Wk, Wv, bq, bk, bv, Qp, Kp, Vp);

    dim3 ga(16, 32);   // x = bh (XCD locality for K/V), y = q-tile
    attn_k<<<ga, 256, 0, stream>>>(Qp, Kp, Vp, mask, Ob);

    dim3 go(32, 4);
    out_gemm<<<go, 256, 0, stream>>>(Ob, Wo, bo, (float*)d_out);
}

// Round 4
// 87.547 us; speedup vs baseline: 1.5116x; 1.2895x over previous
//
#include <hip/hip_runtime.h>

typedef unsigned short u16;
typedef __attribute__((ext_vector_type(8))) short short8;
typedef __attribute__((ext_vector_type(8))) __bf16 bf16x8;
typedef __attribute__((ext_vector_type(4))) float f32x4;
typedef __attribute__((ext_vector_type(4))) unsigned int u32x4;

#define MFMA_BF16(a, b, c) __builtin_amdgcn_mfma_f32_16x16x32_bf16((a), (b), (c), 0, 0, 0)

__device__ __forceinline__ u16 f2bf(float f) {
    unsigned u = __builtin_bit_cast(unsigned, f);
    u += 0x7FFFu + ((u >> 16) & 1u);   // round-to-nearest-even; inputs finite
    return (u16)(u >> 16);
}

__device__ __forceinline__ unsigned pack_bf2(float lo, float hi) {
    return (unsigned)f2bf(lo) | ((unsigned)f2bf(hi) << 16);
}

// ---------------------------------------------------------------------------
// Projection GEMM: O[n][c] = bf16( (X[n][:] . W[c][:] + b[c]) * alpha )
// alpha_q = SCALE * log2(e) so attention softmax can use exp2 directly.
// ---------------------------------------------------------------------------
__global__ __launch_bounds__(256) void proj_gemm(
    const float* __restrict__ Xq, const float* __restrict__ Xk, const float* __restrict__ Xv,
    const float* __restrict__ Wq, const float* __restrict__ Wk, const float* __restrict__ Wv,
    const float* __restrict__ bq, const float* __restrict__ bk, const float* __restrict__ bv,
    u16* __restrict__ Oq, u16* __restrict__ Ok, u16* __restrict__ Ov)
{
    constexpr int K = 512, N = 512;
    const int z = blockIdx.z;
    const float* __restrict__ X = (z == 0) ? Xq : (z == 1) ? Xk : Xv;
    const float* __restrict__ W = (z == 0) ? Wq : (z == 1) ? Wk : Wv;
    const float* __restrict__ bias = (z == 0) ? bq : (z == 1) ? bk : bv;
    u16* __restrict__ O = (z == 0) ? Oq : (z == 1) ? Ok : Ov;
    const float alpha = (z == 0) ? 0.125f * 1.44269504088896f : 1.0f;

    __shared__ u16 lA[128 * 64];
    __shared__ u16 lB[128 * 64];

    const int tid = threadIdx.x, lane = tid & 63, w = tid >> 6;
    const int wr = w >> 1, wc = w & 1;
    const int bm = blockIdx.x, bn = blockIdx.y;
    const int r0 = tid >> 3, cc = tid & 7;

    f32x4 acc[4][4];
    for (int m = 0; m < 4; ++m)
        for (int n = 0; n < 4; ++n)
            acc[m][n] = f32x4{0.f, 0.f, 0.f, 0.f};

    for (int kt = 0; kt < K; kt += 64) {
        __syncthreads();
        for (int p = 0; p < 4; ++p) {
            int r = r0 + p * 32;
            {
                const float4* g = (const float4*)(X + (size_t)(bm * 128 + r) * K + kt + cc * 8);
                float4 f0 = g[0], f1 = g[1];
                short8 v;
                v[0] = (short)f2bf(f0.x); v[1] = (short)f2bf(f0.y);
                v[2] = (short)f2bf(f0.z); v[3] = (short)f2bf(f0.w);
                v[4] = (short)f2bf(f1.x); v[5] = (short)f2bf(f1.y);
                v[6] = (short)f2bf(f1.z); v[7] = (short)f2bf(f1.w);
                *(short8*)&lA[r * 64 + ((cc ^ (r & 7)) << 3)] = v;
            }
            {
                const float4* g = (const float4*)(W + (size_t)(bn * 128 + r) * K + kt + cc * 8);
                float4 f0 = g[0], f1 = g[1];
                short8 v;
                v[0] = (short)f2bf(f0.x); v[1] = (short)f2bf(f0.y);
                v[2] = (short)f2bf(f0.z); v[3] = (short)f2bf(f0.w);
                v[4] = (short)f2bf(f1.x); v[5] = (short)f2bf(f1.y);
                v[6] = (short)f2bf(f1.z); v[7] = (short)f2bf(f1.w);
                *(short8*)&lB[r * 64 + ((cc ^ (r & 7)) << 3)] = v;
            }
        }
        __syncthreads();
        for (int kk = 0; kk < 2; ++kk) {
            bf16x8 af[4], bfr[4];
            for (int m = 0; m < 4; ++m) {
                int row = wr * 64 + m * 16 + (lane & 15);
                af[m] = *(const bf16x8*)&lA[row * 64 + (((kk * 4 + (lane >> 4)) ^ (row & 7)) << 3)];
            }
            for (int n = 0; n < 4; ++n) {
                int row = wc * 64 + n * 16 + (lane & 15);
                bfr[n] = *(const bf16x8*)&lB[row * 64 + (((kk * 4 + (lane >> 4)) ^ (row & 7)) << 3)];
            }
            for (int m = 0; m < 4; ++m)
                for (int n = 0; n < 4; ++n)
                    acc[m][n] = MFMA_BF16(af[m], bfr[n], acc[m][n]);
        }
    }
    for (int m = 0; m < 4; ++m)
        for (int n = 0; n < 4; ++n) {
            int row = bm * 128 + wr * 64 + m * 16 + ((lane >> 4) << 2);
            int col = bn * 128 + wc * 64 + n * 16 + (lane & 15);
            float bv_ = bias[col];
            for (int i = 0; i < 4; ++i) {
                float v = (acc[m][n][i] + bv_) * alpha;
                O[(size_t)(row + i) * N + col] = f2bf(v);
            }
        }
}

// ---------------------------------------------------------------------------
// Output GEMM
// ---------------------------------------------------------------------------
__global__ __launch_bounds__(256) void out_gemm(
    const u16* __restrict__ A, const float* __restrict__ W,
    const float* __restrict__ bias, float* __restrict__ O)
{
    constexpr int K = 512, N = 512;
    __shared__ u16 lA[128 * 64];
    __shared__ u16 lB[128 * 64];

    const int tid = threadIdx.x, lane = tid & 63, w = tid >> 6;
    const int wr = w >> 1, wc = w & 1;
    const int bm = blockIdx.x, bn = blockIdx.y;
    const int r0 = tid >> 3, cc = tid & 7;

    f32x4 acc[4][4];
    for (int m = 0; m < 4; ++m)
        for (int n = 0; n < 4; ++n)
            acc[m][n] = f32x4{0.f, 0.f, 0.f, 0.f};

    for (int kt = 0; kt < K; kt += 64) {
        __syncthreads();
        for (int p = 0; p < 4; ++p) {
            int r = r0 + p * 32;
            *(short8*)&lA[r * 64 + ((cc ^ (r & 7)) << 3)] =
                *(const short8*)(A + (size_t)(bm * 128 + r) * K + kt + cc * 8);
            const float4* g = (const float4*)(W + (size_t)(bn * 128 + r) * K + kt + cc * 8);
            float4 f0 = g[0], f1 = g[1];
            short8 v;
            v[0] = (short)f2bf(f0.x); v[1] = (short)f2bf(f0.y);
            v[2] = (short)f2bf(f0.z); v[3] = (short)f2bf(f0.w);
            v[4] = (short)f2bf(f1.x); v[5] = (short)f2bf(f1.y);
            v[6] = (short)f2bf(f1.z); v[7] = (short)f2bf(f1.w);
            *(short8*)&lB[r * 64 + ((cc ^ (r & 7)) << 3)] = v;
        }
        __syncthreads();
        for (int kk = 0; kk < 2; ++kk) {
            bf16x8 af[4], bfr[4];
            for (int m = 0; m < 4; ++m) {
                int row = wr * 64 + m * 16 + (lane & 15);
                af[m] = *(const bf16x8*)&lA[row * 64 + (((kk * 4 + (lane >> 4)) ^ (row & 7)) << 3)];
            }
            for (int n = 0; n < 4; ++n) {
                int row = wc * 64 + n * 16 + (lane & 15);
                bfr[n] = *(const bf16x8*)&lB[row * 64 + (((kk * 4 + (lane >> 4)) ^ (row & 7)) << 3)];
            }
            for (int m = 0; m < 4; ++m)
                for (int n = 0; n < 4; ++n)
                    acc[m][n] = MFMA_BF16(af[m], bfr[n], acc[m][n]);
        }
    }
    for (int m = 0; m < 4; ++m)
        for (int n = 0; n < 4; ++n) {
            int row = bm * 128 + wr * 64 + m * 16 + ((lane >> 4) << 2);
            int col = bn * 128 + wc * 64 + n * 16 + (lane & 15);
            float bv_ = bias[col];
            for (int i = 0; i < 4; ++i)
                O[(size_t)(row + i) * N + col] = acc[m][n][i] + bv_;
        }
}

// ---------------------------------------------------------------------------
// Flash attention v3: swapped QK^T, zero-shuffle PV via k-slot remapping,
// conflict-free V^T scatter (enriched swizzle), exp2 softmax, defer-max.
//
// lV layout: V[kv][d] at u16 addr d*64 + (((kv>>3) ^ sw(d))<<3) + (kv&7),
//            sw(d) = (d + (d>>3)) & 7.
// PV k-slot map: slot(gd,e) -> kv = 32*kb + 16*(e>>2) + 4*gd + (e&3); both
// A (held p regs) and B (lV b64 reads) use it, so no cross-lane exchange.
// ---------------------------------------------------------------------------
__global__ __launch_bounds__(256) void attn_k(
    const u16* __restrict__ Qp, const u16* __restrict__ Kp, const u16* __restrict__ Vp,
    const unsigned char* __restrict__ mask, u16* __restrict__ Ob)
{
    constexpr int C = 512, NK = 2048, NT = NK / 64;
    __shared__ u16 lK[2][64 * 64];
    __shared__ u16 lV[2][64 * 64];

    const int tid = threadIdx.x, lane = tid & 63, w = tid >> 6;
    const int gd = lane >> 4, q15 = lane & 15;
    const int bh = blockIdx.x, qb = blockIdx.y;
    const int b = bh >> 3, h = bh & 7;
    const size_t qrow0 = (size_t)b * 2048 + qb * 64;
    const size_t krow0 = (size_t)b * 2048;
    const int col0 = h * 64;
    const int rs = tid >> 3, cc = tid & 7;

    // Q fragments in registers (B-operand): lane holds Q[q15][kb*32+gd*8 ..+8]
    bf16x8 qf[2];
    {
        const u16* qrow = Qp + (qrow0 + w * 16 + q15) * C + col0;
        qf[0] = *(const bf16x8*)(qrow + gd * 8);
        qf[1] = *(const bf16x8*)(qrow + 32 + gd * 8);
    }

    float mst = -1e30f, lst = 0.f;   // log2-domain running max / sum
    f32x4 oacc[4];
    #pragma unroll
    for (int i = 0; i < 4; ++i) oacc[i] = f32x4{0.f, 0.f, 0.f, 0.f};

    // prologue: stage tile 0 into buffer 0
    #pragma unroll
    for (int p = 0; p < 2; ++p) {
        int r = rs + p * 32;
        *(short8*)&lK[0][r * 64 + ((cc ^ (r & 7)) << 3)] =
            *(const short8*)(Kp + (krow0 + r) * C + col0 + cc * 8);
        short8 vv = *(const short8*)(Vp + (krow0 + r) * C + col0 + cc * 8);
        #pragma unroll
        for (int j = 0; j < 8; ++j)
            lV[0][(cc * 8 + j) * 64 + ((((r >> 3) ^ ((j + cc) & 7))) << 3) + (r & 7)] = (u16)vv[j];
    }
    __syncthreads();

    int cur = 0;
    for (int t = 0; t < NT; ++t) {
        const int kv = t * 64;
        const bool hasnext = (t + 1 < NT);
        short8 kreg[2], vreg[2];
        if (hasnext) {
            #pragma unroll
            for (int p = 0; p < 2; ++p) {
                int r = rs + p * 32;
                kreg[p] = *(const short8*)(Kp + (krow0 + kv + 64 + r) * C + col0 + cc * 8);
                vreg[p] = *(const short8*)(Vp + (krow0 + kv + 64 + r) * C + col0 + cc * 8);
            }
        }
        unsigned char mbyte = mask[(size_t)b * NK + kv + lane];

        // QK^T swapped: lane holds S^T[16*t4+4*gd+i][q15]
        f32x4 s[4];
        #pragma unroll
        for (int i = 0; i < 4; ++i) s[i] = f32x4{0.f, 0.f, 0.f, 0.f};
        const u16* Kc = &lK[cur][0];
        __builtin_amdgcn_s_setprio(1);
        #pragma unroll
        for (int kb = 0; kb < 2; ++kb)
            #pragma unroll
            for (int t4 = 0; t4 < 4; ++t4) {
                int krow = t4 * 16 + q15;
                bf16x8 kf = *(const bf16x8*)&Kc[krow * 64 + (((kb * 4 + gd) ^ (krow & 7)) << 3)];
                s[t4] = MFMA_BF16(kf, qf[kb], s[t4]);
            }
        __builtin_amdgcn_s_setprio(0);

        // key-padding mask (uniform branch; all-false for this input)
        unsigned long long mb = __ballot(mbyte != 0);
        if (mb) {
            #pragma unroll
            for (int t4 = 0; t4 < 4; ++t4)
                #pragma unroll
                for (int i = 0; i < 4; ++i) {
                    int k = t4 * 16 + gd * 4 + i;
                    if ((mb >> k) & 1ull) s[t4][i] = -1e30f;
                }
        }

        // online softmax (exp2 domain; scale*log2e folded into Q)
        float pmax = s[0][0];
        #pragma unroll
        for (int t4 = 0; t4 < 4; ++t4)
            #pragma unroll
            for (int i = 0; i < 4; ++i) pmax = fmaxf(pmax, s[t4][i]);
        pmax = fmaxf(pmax, __shfl_xor(pmax, 16));
        pmax = fmaxf(pmax, __shfl_xor(pmax, 32));

        // defer-max (T13): only rescale when some row grew by > 11 (log2)
        if (!__all(pmax - mst <= 11.0f)) {
            float mn = fmaxf(mst, pmax);
            float sf = exp2f(mst - mn);
            mst = mn;
            lst *= sf;
            #pragma unroll
            for (int i = 0; i < 4; ++i) {
                float sfi = __shfl(sf, (lane & 48) | ((gd << 2) + i));
                #pragma unroll
                for (int t2 = 0; t2 < 4; ++t2) oacc[t2][i] *= sfi;
            }
        }

        float p[4][4];
        float rsum = 0.f;
        #pragma unroll
        for (int t4 = 0; t4 < 4; ++t4)
            #pragma unroll
            for (int i = 0; i < 4; ++i) {
                float e = exp2f(s[t4][i] - mst);
                p[t4][i] = e;
                rsum += e;
            }
        rsum += __shfl_xor(rsum, 16);
        rsum += __shfl_xor(rsum, 32);
        lst += rsum;

        // PV with k-slot remap: A-frag straight from held p regs (no shuffles)
        const u16* Vc = &lV[cur][0];
        __builtin_amdgcn_s_setprio(1);
        #pragma unroll
        for (int kb = 0; kb < 2; ++kb) {
            u32x4 pw;
            pw[0] = pack_bf2(p[2 * kb][0], p[2 * kb][1]);
            pw[1] = pack_bf2(p[2 * kb][2], p[2 * kb][3]);
            pw[2] = pack_bf2(p[2 * kb + 1][0], p[2 * kb + 1][1]);
            pw[3] = pack_bf2(p[2 * kb + 1][2], p[2 * kb + 1][3]);
            bf16x8 pa = __builtin_bit_cast(bf16x8, pw);
            #pragma unroll
            for (int t2 = 0; t2 < 4; ++t2) {
                int d = t2 * 16 + q15;
                int swd = (d + (d >> 3)) & 7;
                int base = d * 64 + 4 * (gd & 1);
                uint2 v0 = *(const uint2*)&Vc[base + (((4 * kb + 0 + (gd >> 1)) ^ swd) << 3)];
                uint2 v1 = *(const uint2*)&Vc[base + (((4 * kb + 2 + (gd >> 1)) ^ swd) << 3)];
                u32x4 vw; vw[0] = v0.x; vw[1] = v0.y; vw[2] = v1.x; vw[3] = v1.y;
                bf16x8 vf = __builtin_bit_cast(bf16x8, vw);
                oacc[t2] = MFMA_BF16(pa, vf, oacc[t2]);
            }
        }
        __builtin_amdgcn_s_setprio(0);

        // write next tile into the other buffer, single barrier per tile
        if (hasnext) {
            int nxt = cur ^ 1;
            #pragma unroll
            for (int p = 0; p < 2; ++p) {
                int r = rs + p * 32;
                *(short8*)&lK[nxt][r * 64 + ((cc ^ (r & 7)) << 3)] = kreg[p];
                #pragma unroll
                for (int j = 0; j < 8; ++j)
                    lV[nxt][(cc * 8 + j) * 64 + ((((r >> 3) ^ ((j + cc) & 7))) << 3) + (r & 7)] = (u16)vreg[p][j];
            }
            __syncthreads();
            cur = nxt;
        }
    }

    // epilogue: normalize and store
    #pragma unroll
    for (int i = 0; i < 4; ++i) {
        float li = __shfl(lst, (lane & 48) | ((gd << 2) + i));
        float inv = 1.f / li;
        int qg = qb * 64 + w * 16 + gd * 4 + i;
        #pragma unroll
        for (int t2 = 0; t2 < 4; ++t2) {
            int col = col0 + t2 * 16 + q15;
            Ob[((size_t)b * 2048 + qg) * C + col] = f2bf(oacc[t2][i] * inv);
        }
    }
}

extern "C" void kernel_launch(void* const* d_in, const int* in_sizes, int n_in,
                              void* d_out, int out_size, void* d_ws, size_t ws_size,
                              hipStream_t stream) {
    const float* query = (const float*)d_in[0];
    const float* key   = (const float*)d_in[1];
    const float* value = (const float*)d_in[2];
    const unsigned char* mask = (const unsigned char*)d_in[3];
    const float* Wq = (const float*)d_in[4];
    const float* bq = (const float*)d_in[5];
    const float* Wk = (const float*)d_in[6];
    const float* bk = (const float*)d_in[7];
    const float* Wv = (const float*)d_in[8];
    const float* bv = (const float*)d_in[9];
    const float* Wo = (const float*)d_in[10];
    const float* bo = (const float*)d_in[11];

    u16* ws = (u16*)d_ws;
    u16* Qp = ws;
    u16* Kp = ws + 2097152;
    u16* Vp = ws + 4194304;
    u16* Ob = ws + 6291456;

    dim3 gp(32, 4, 3);
    proj_gemm<<<gp, 256, 0, stream>>>(query, key, value, Wq, Wk, Wv, bq, bk, bv, Qp, Kp, Vp);

    dim3 ga(16, 32);   // x = bh (XCD locality for K/V), y = q-tile
    attn_k<<<ga, 256, 0, stream>>>(Qp, Kp, Vp, mask, Ob);

    dim3 go(32, 4);
    out_gemm<<<go, 256, 0, stream>>>(Ob, Wo, bo, (float*)d_out);
}

// Round 5
// 72.374 us; speedup vs baseline: 1.8285x; 1.2096x over previous
//
#include <hip/hip_runtime.h>

typedef unsigned short u16;
typedef __attribute__((ext_vector_type(8))) short short8;
typedef __attribute__((ext_vector_type(8))) __bf16 bf16x8;
typedef __attribute__((ext_vector_type(4))) float f32x4;
typedef __attribute__((ext_vector_type(4))) unsigned int u32x4;

#define MFMA_BF16(a, b, c) __builtin_amdgcn_mfma_f32_16x16x32_bf16((a), (b), (c), 0, 0, 0)

__device__ __forceinline__ u16 f2bf(float f) {
    unsigned u = __builtin_bit_cast(unsigned, f);
    u += 0x7FFFu + ((u >> 16) & 1u);   // round-to-nearest-even; inputs finite
    return (u16)(u >> 16);
}

// v_cvt_pk_bf16_f32: dst = {bf16(lo), bf16(hi)} packed, RNE
__device__ __forceinline__ unsigned cvt_pk_bf16(float lo, float hi) {
    unsigned r;
    asm("v_cvt_pk_bf16_f32 %0, %1, %2" : "=v"(r) : "v"(lo), "v"(hi));
    return r;
}

// raw v_exp_f32 (exp2); denormal range flushes to 0, which is what we want
__device__ __forceinline__ float fast_exp2(float x) {
    float r;
    asm("v_exp_f32 %0, %1" : "=v"(r) : "v"(x));
    return r;
}

// ---------------------------------------------------------------------------
// Projection GEMM: O[n][c] = bf16( (X[n][:] . W[c][:] + b[c]) * alpha )
// alpha_q = SCALE * log2(e) so attention softmax can use exp2 directly.
// ---------------------------------------------------------------------------
__global__ __launch_bounds__(256) void proj_gemm(
    const float* __restrict__ Xq, const float* __restrict__ Xk, const float* __restrict__ Xv,
    const float* __restrict__ Wq, const float* __restrict__ Wk, const float* __restrict__ Wv,
    const float* __restrict__ bq, const float* __restrict__ bk, const float* __restrict__ bv,
    u16* __restrict__ Oq, u16* __restrict__ Ok, u16* __restrict__ Ov)
{
    constexpr int K = 512, N = 512;
    const int z = blockIdx.z;
    const float* __restrict__ X = (z == 0) ? Xq : (z == 1) ? Xk : Xv;
    const float* __restrict__ W = (z == 0) ? Wq : (z == 1) ? Wk : Wv;
    const float* __restrict__ bias = (z == 0) ? bq : (z == 1) ? bk : bv;
    u16* __restrict__ O = (z == 0) ? Oq : (z == 1) ? Ok : Ov;
    const float alpha = (z == 0) ? 0.125f * 1.44269504088896f : 1.0f;

    __shared__ u16 lA[128 * 64];
    __shared__ u16 lB[128 * 64];

    const int tid = threadIdx.x, lane = tid & 63, w = tid >> 6;
    const int wr = w >> 1, wc = w & 1;
    const int bm = blockIdx.x, bn = blockIdx.y;
    const int r0 = tid >> 3, cc = tid & 7;

    f32x4 acc[4][4];
    for (int m = 0; m < 4; ++m)
        for (int n = 0; n < 4; ++n)
            acc[m][n] = f32x4{0.f, 0.f, 0.f, 0.f};

    for (int kt = 0; kt < K; kt += 64) {
        __syncthreads();
        for (int p = 0; p < 4; ++p) {
            int r = r0 + p * 32;
            {
                const float4* g = (const float4*)(X + (size_t)(bm * 128 + r) * K + kt + cc * 8);
                float4 f0 = g[0], f1 = g[1];
                short8 v;
                v[0] = (short)f2bf(f0.x); v[1] = (short)f2bf(f0.y);
                v[2] = (short)f2bf(f0.z); v[3] = (short)f2bf(f0.w);
                v[4] = (short)f2bf(f1.x); v[5] = (short)f2bf(f1.y);
                v[6] = (short)f2bf(f1.z); v[7] = (short)f2bf(f1.w);
                *(short8*)&lA[r * 64 + ((cc ^ (r & 7)) << 3)] = v;
            }
            {
                const float4* g = (const float4*)(W + (size_t)(bn * 128 + r) * K + kt + cc * 8);
                float4 f0 = g[0], f1 = g[1];
                short8 v;
                v[0] = (short)f2bf(f0.x); v[1] = (short)f2bf(f0.y);
                v[2] = (short)f2bf(f0.z); v[3] = (short)f2bf(f0.w);
                v[4] = (short)f2bf(f1.x); v[5] = (short)f2bf(f1.y);
                v[6] = (short)f2bf(f1.z); v[7] = (short)f2bf(f1.w);
                *(short8*)&lB[r * 64 + ((cc ^ (r & 7)) << 3)] = v;
            }
        }
        __syncthreads();
        for (int kk = 0; kk < 2; ++kk) {
            bf16x8 af[4], bfr[4];
            for (int m = 0; m < 4; ++m) {
                int row = wr * 64 + m * 16 + (lane & 15);
                af[m] = *(const bf16x8*)&lA[row * 64 + (((kk * 4 + (lane >> 4)) ^ (row & 7)) << 3)];
            }
            for (int n = 0; n < 4; ++n) {
                int row = wc * 64 + n * 16 + (lane & 15);
                bfr[n] = *(const bf16x8*)&lB[row * 64 + (((kk * 4 + (lane >> 4)) ^ (row & 7)) << 3)];
            }
            for (int m = 0; m < 4; ++m)
                for (int n = 0; n < 4; ++n)
                    acc[m][n] = MFMA_BF16(af[m], bfr[n], acc[m][n]);
        }
    }
    for (int m = 0; m < 4; ++m)
        for (int n = 0; n < 4; ++n) {
            int row = bm * 128 + wr * 64 + m * 16 + ((lane >> 4) << 2);
            int col = bn * 128 + wc * 64 + n * 16 + (lane & 15);
            float bv_ = bias[col];
            for (int i = 0; i < 4; ++i) {
                float v = (acc[m][n][i] + bv_) * alpha;
                O[(size_t)(row + i) * N + col] = f2bf(v);
            }
        }
}

// ---------------------------------------------------------------------------
// Output GEMM
// ---------------------------------------------------------------------------
__global__ __launch_bounds__(256) void out_gemm(
    const u16* __restrict__ A, const float* __restrict__ W,
    const float* __restrict__ bias, float* __restrict__ O)
{
    constexpr int K = 512, N = 512;
    __shared__ u16 lA[128 * 64];
    __shared__ u16 lB[128 * 64];

    const int tid = threadIdx.x, lane = tid & 63, w = tid >> 6;
    const int wr = w >> 1, wc = w & 1;
    const int bm = blockIdx.x, bn = blockIdx.y;
    const int r0 = tid >> 3, cc = tid & 7;

    f32x4 acc[4][4];
    for (int m = 0; m < 4; ++m)
        for (int n = 0; n < 4; ++n)
            acc[m][n] = f32x4{0.f, 0.f, 0.f, 0.f};

    for (int kt = 0; kt < K; kt += 64) {
        __syncthreads();
        for (int p = 0; p < 4; ++p) {
            int r = r0 + p * 32;
            *(short8*)&lA[r * 64 + ((cc ^ (r & 7)) << 3)] =
                *(const short8*)(A + (size_t)(bm * 128 + r) * K + kt + cc * 8);
            const float4* g = (const float4*)(W + (size_t)(bn * 128 + r) * K + kt + cc * 8);
            float4 f0 = g[0], f1 = g[1];
            short8 v;
            v[0] = (short)f2bf(f0.x); v[1] = (short)f2bf(f0.y);
            v[2] = (short)f2bf(f0.z); v[3] = (short)f2bf(f0.w);
            v[4] = (short)f2bf(f1.x); v[5] = (short)f2bf(f1.y);
            v[6] = (short)f2bf(f1.z); v[7] = (short)f2bf(f1.w);
            *(short8*)&lB[r * 64 + ((cc ^ (r & 7)) << 3)] = v;
        }
        __syncthreads();
        for (int kk = 0; kk < 2; ++kk) {
            bf16x8 af[4], bfr[4];
            for (int m = 0; m < 4; ++m) {
                int row = wr * 64 + m * 16 + (lane & 15);
                af[m] = *(const bf16x8*)&lA[row * 64 + (((kk * 4 + (lane >> 4)) ^ (row & 7)) << 3)];
            }
            for (int n = 0; n < 4; ++n) {
                int row = wc * 64 + n * 16 + (lane & 15);
                bfr[n] = *(const bf16x8*)&lB[row * 64 + (((kk * 4 + (lane >> 4)) ^ (row & 7)) << 3)];
            }
            for (int m = 0; m < 4; ++m)
                for (int n = 0; n < 4; ++n)
                    acc[m][n] = MFMA_BF16(af[m], bfr[n], acc[m][n]);
        }
    }
    for (int m = 0; m < 4; ++m)
        for (int n = 0; n < 4; ++n) {
            int row = bm * 128 + wr * 64 + m * 16 + ((lane >> 4) << 2);
            int col = bn * 128 + wc * 64 + n * 16 + (lane & 15);
            float bv_ = bias[col];
            for (int i = 0; i < 4; ++i)
                O[(size_t)(row + i) * N + col] = acc[m][n][i] + bv_;
        }
}

// ---------------------------------------------------------------------------
// Flash attention v4: two-tile pairing (T15), shuffle-free softmax common path,
// cvt_pk P-packing, raw v_exp. One barrier per KV-tile PAIR.
// 4 LDS buffer sets (64 KB). Zero-shuffle PV via k-slot remap (round-4).
// ---------------------------------------------------------------------------
__global__ __launch_bounds__(256) void attn_k(
    const u16* __restrict__ Qp, const u16* __restrict__ Kp, const u16* __restrict__ Vp,
    const unsigned char* __restrict__ mask, u16* __restrict__ Ob)
{
    constexpr int C = 512, NK = 2048, NP = NK / 128;   // 16 pairs
    __shared__ u16 lK[2][2][64 * 64];
    __shared__ u16 lV[2][2][64 * 64];

    const int tid = threadIdx.x, lane = tid & 63, w = tid >> 6;
    const int gd = lane >> 4, q15 = lane & 15;
    const int bh = blockIdx.x, qb = blockIdx.y;
    const int b = bh >> 3, h = bh & 7;
    const size_t qrow0 = (size_t)b * 2048 + qb * 64;
    const size_t krow0 = (size_t)b * 2048;
    const int col0 = h * 64;
    const int rs = tid >> 3, cc = tid & 7;

    // Q fragments in registers (B-operand): lane holds Q[q15][kb*32+gd*8 ..+8]
    bf16x8 qf[2];
    {
        const u16* qrow = Qp + (qrow0 + w * 16 + q15) * C + col0;
        qf[0] = *(const bf16x8*)(qrow + gd * 8);
        qf[1] = *(const bf16x8*)(qrow + 32 + gd * 8);
    }

    float mst = -1e30f, lstp = 0.f;   // running max (row-uniform) / per-lane partial sum
    f32x4 oacc[4];
    #pragma unroll
    for (int i = 0; i < 4; ++i) oacc[i] = f32x4{0.f, 0.f, 0.f, 0.f};

    // prologue: stage tiles 0,1 into pair-buffer 0
    {
        short8 kr[2][2], vr[2][2];
        #pragma unroll
        for (int u = 0; u < 2; ++u)
            #pragma unroll
            for (int p = 0; p < 2; ++p) {
                int r = rs + p * 32;
                kr[u][p] = *(const short8*)(Kp + (krow0 + u * 64 + r) * C + col0 + cc * 8);
                vr[u][p] = *(const short8*)(Vp + (krow0 + u * 64 + r) * C + col0 + cc * 8);
            }
        #pragma unroll
        for (int u = 0; u < 2; ++u)
            #pragma unroll
            for (int p = 0; p < 2; ++p) {
                int r = rs + p * 32;
                *(short8*)&lK[0][u][r * 64 + ((cc ^ (r & 7)) << 3)] = kr[u][p];
                #pragma unroll
                for (int j = 0; j < 8; ++j)
                    lV[0][u][(cc * 8 + j) * 64 + (((r >> 3) ^ ((j + cc) & 7)) << 3) + (r & 7)] = (u16)vr[u][p][j];
            }
    }
    __syncthreads();

    int cur = 0;
    for (int pj = 0; pj < NP; ++pj) {
        const int kv = pj * 128;
        const bool hasnext = (pj + 1 < NP);
        short8 kreg[2][2], vreg[2][2];
        if (hasnext) {
            #pragma unroll
            for (int u = 0; u < 2; ++u)
                #pragma unroll
                for (int p = 0; p < 2; ++p) {
                    int r = rs + p * 32;
                    kreg[u][p] = *(const short8*)(Kp + (krow0 + kv + 128 + u * 64 + r) * C + col0 + cc * 8);
                    vreg[u][p] = *(const short8*)(Vp + (krow0 + kv + 128 + u * 64 + r) * C + col0 + cc * 8);
                }
        }
        unsigned char mby[2];
        mby[0] = mask[(size_t)b * NK + kv + lane];
        mby[1] = mask[(size_t)b * NK + kv + 64 + lane];

        // QK^T for both tiles of the pair (independent MFMA chains)
        f32x4 s2[2][4];
        #pragma unroll
        for (int u = 0; u < 2; ++u)
            #pragma unroll
            for (int i = 0; i < 4; ++i) s2[u][i] = f32x4{0.f, 0.f, 0.f, 0.f};
        __builtin_amdgcn_s_setprio(1);
        #pragma unroll
        for (int u = 0; u < 2; ++u) {
            const u16* Kc = &lK[cur][u][0];
            #pragma unroll
            for (int kb = 0; kb < 2; ++kb)
                #pragma unroll
                for (int t4 = 0; t4 < 4; ++t4) {
                    int krow = t4 * 16 + q15;
                    bf16x8 kf = *(const bf16x8*)&Kc[krow * 64 + (((kb * 4 + gd) ^ (krow & 7)) << 3)];
                    s2[u][t4] = MFMA_BF16(kf, qf[kb], s2[u][t4]);
                }
        }
        __builtin_amdgcn_s_setprio(0);

        // softmax + PV per tile (PV(u=0) overlaps SM(u=1) scheduling)
        #pragma unroll
        for (int u = 0; u < 2; ++u) {
            // key-padding mask (uniform branch; all-false for this input)
            unsigned long long m64 = __ballot(mby[u] != 0);
            if (m64) {
                #pragma unroll
                for (int t4 = 0; t4 < 4; ++t4)
                    #pragma unroll
                    for (int i = 0; i < 4; ++i) {
                        int k = t4 * 16 + gd * 4 + i;
                        if ((m64 >> k) & 1ull) s2[u][t4][i] = -1e30f;
                    }
            }

            // lane-local max; defer-max check needs no cross-lane reduce
            float pmax = s2[u][0][0];
            #pragma unroll
            for (int t4 = 0; t4 < 4; ++t4)
                #pragma unroll
                for (int i = 0; i < 4; ++i) pmax = fmaxf(pmax, s2[u][t4][i]);

            if (!__all(pmax - mst <= 11.0f)) {
                // rare: full row-max reduce + rescale
                float rm = fmaxf(pmax, __shfl_xor(pmax, 16));
                rm = fmaxf(rm, __shfl_xor(rm, 32));
                float mn = fmaxf(mst, rm);
                float sf = exp2f(mst - mn);
                mst = mn;
                lstp *= sf;
                #pragma unroll
                for (int i = 0; i < 4; ++i) {
                    float sfi = __shfl(sf, (lane & 48) | ((gd << 2) + i));
                    #pragma unroll
                    for (int t2 = 0; t2 < 4; ++t2) oacc[t2][i] *= sfi;
                }
            }

            float p[4][4];
            float rsum = 0.f;
            #pragma unroll
            for (int t4 = 0; t4 < 4; ++t4)
                #pragma unroll
                for (int i = 0; i < 4; ++i) {
                    float e = fast_exp2(s2[u][t4][i] - mst);
                    p[t4][i] = e;
                    rsum += e;
                }
            lstp += rsum;   // per-lane partial; reduced once in epilogue

            // PV with k-slot remap: A-frag from held p regs (no shuffles)
            const u16* Vc = &lV[cur][u][0];
            __builtin_amdgcn_s_setprio(1);
            #pragma unroll
            for (int kb = 0; kb < 2; ++kb) {
                u32x4 pw;
                pw[0] = cvt_pk_bf16(p[2 * kb][0], p[2 * kb][1]);
                pw[1] = cvt_pk_bf16(p[2 * kb][2], p[2 * kb][3]);
                pw[2] = cvt_pk_bf16(p[2 * kb + 1][0], p[2 * kb + 1][1]);
                pw[3] = cvt_pk_bf16(p[2 * kb + 1][2], p[2 * kb + 1][3]);
                bf16x8 pa = __builtin_bit_cast(bf16x8, pw);
                #pragma unroll
                for (int t2 = 0; t2 < 4; ++t2) {
                    int d = t2 * 16 + q15;
                    int swd = (d + (d >> 3)) & 7;
                    int base = d * 64 + 4 * (gd & 1);
                    uint2 v0 = *(const uint2*)&Vc[base + (((4 * kb + 0 + (gd >> 1)) ^ swd) << 3)];
                    uint2 v1 = *(const uint2*)&Vc[base + (((4 * kb + 2 + (gd >> 1)) ^ swd) << 3)];
                    u32x4 vw; vw[0] = v0.x; vw[1] = v0.y; vw[2] = v1.x; vw[3] = v1.y;
                    bf16x8 vf = __builtin_bit_cast(bf16x8, vw);
                    oacc[t2] = MFMA_BF16(pa, vf, oacc[t2]);
                }
            }
            __builtin_amdgcn_s_setprio(0);
        }

        // stage next pair into the other buffer set; one barrier per pair
        if (hasnext) {
            int nxt = cur ^ 1;
            #pragma unroll
            for (int u = 0; u < 2; ++u)
                #pragma unroll
                for (int p = 0; p < 2; ++p) {
                    int r = rs + p * 32;
                    *(short8*)&lK[nxt][u][r * 64 + ((cc ^ (r & 7)) << 3)] = kreg[u][p];
                    #pragma unroll
                    for (int j = 0; j < 8; ++j)
                        lV[nxt][u][(cc * 8 + j) * 64 + (((r >> 3) ^ ((j + cc) & 7)) << 3) + (r & 7)] = (u16)vreg[u][p][j];
                }
            __syncthreads();
            cur = nxt;
        }
    }

    // epilogue: reduce per-lane partial sums (row group = lanes differing in bits 4-5)
    float lsum = lstp + __shfl_xor(lstp, 16);
    lsum += __shfl_xor(lsum, 32);

    #pragma unroll
    for (int i = 0; i < 4; ++i) {
        float li = __shfl(lsum, (lane & 48) | ((gd << 2) + i));
        float inv = 1.f / li;
        int qg = qb * 64 + w * 16 + gd * 4 + i;
        #pragma unroll
        for (int t2 = 0; t2 < 4; ++t2) {
            int col = col0 + t2 * 16 + q15;
            Ob[((size_t)b * 2048 + qg) * C + col] = f2bf(oacc[t2][i] * inv);
        }
    }
}

extern "C" void kernel_launch(void* const* d_in, const int* in_sizes, int n_in,
                              void* d_out, int out_size, void* d_ws, size_t ws_size,
                              hipStream_t stream) {
    const float* query = (const float*)d_in[0];
    const float* key   = (const float*)d_in[1];
    const float* value = (const float*)d_in[2];
    const unsigned char* mask = (const unsigned char*)d_in[3];
    const float* Wq = (const float*)d_in[4];
    const float* bq = (const float*)d_in[5];
    const float* Wk = (const float*)d_in[6];
    const float* bk = (const float*)d_in[7];
    const float* Wv = (const float*)d_in[8];
    const float* bv = (const float*)d_in[9];
    const float* Wo = (const float*)d_in[10];
    const float* bo = (const float*)d_in[11];

    u16* ws = (u16*)d_ws;
    u16* Qp = ws;
    u16* Kp = ws + 2097152;
    u16* Vp = ws + 4194304;
    u16* Ob = ws + 6291456;

    dim3 gp(32, 4, 3);
    proj_gemm<<<gp, 256, 0, stream>>>(query, key, value, Wq, Wk, Wv, bq, bk, bv, Qp, Kp, Vp);

    dim3 ga(16, 32);   // x = bh (XCD locality for K/V), y = q-tile
    attn_k<<<ga, 256, 0, stream>>>(Qp, Kp, Vp, mask, Ob);

    dim3 go(32, 4);
    out_gemm<<<go, 256, 0, stream>>>(Ob, Wo, bo, (float*)d_out);
}